// Round 9
// baseline (713.560 us; speedup 1.0000x reference)
//
#include <hip/hip_runtime.h>

typedef __attribute__((ext_vector_type(8))) short short8;
typedef __attribute__((ext_vector_type(4))) float f32x4;
typedef __attribute__((ext_vector_type(4))) unsigned short u16x4;
typedef unsigned short u16;
typedef unsigned int u32;

#define EPSV 1e-6f

__device__ __forceinline__ u16 f2bf(float f){
  u32 u = __float_as_uint(f);
  u = u + 0x7fffu + ((u >> 16) & 1u);
  return (u16)(u >> 16);
}
__device__ __forceinline__ float bf2f(u16 h){
  return __uint_as_float(((u32)h) << 16);
}
__device__ __forceinline__ float sigm(float v){ return 1.f/(1.f + __expf(-v)); }
__device__ __forceinline__ float tanh_fast(float g){
  float e = __expf(-2.f*fabsf(g));
  return copysignf((1.f - e)/(1.f + e), g);
}
__device__ __forceinline__ void gload_lds16(const void* g, void* l){
  __builtin_amdgcn_global_load_lds(
      (const __attribute__((address_space(1))) u32*)g,
      (__attribute__((address_space(3))) u32*)l, 16, 0, 0);
}

// ---------------- ws layout (main path) ----------------
#define WS_WXB   0u           // 1536*512 u16
#define WS_WHB   1572864u
#define WS_CB    3145728u     // 2048 f32
#define WS_SSQP  3153920u     // 16*65536 f32
#define WS_SBF   7348224u     // 65536*512 u16
#define WS_NEED  74457088u

#define GG_SMEM  147456       // A tri-buf 3*16384 (per-wave 4KB slices) + B panel 98304 (fragment-major)

// =====================================================================
// wprep (validated)
// =====================================================================
extern "C" __global__ void wprep(const float* __restrict__ xW, const float* __restrict__ hW,
                                 const float* __restrict__ inw, const float* __restrict__ hidw,
                                 const float* __restrict__ xb, const float* __restrict__ hmixb,
                                 const float* __restrict__ hb,
                                 u16* __restrict__ xWb, u16* __restrict__ hWb,
                                 float* __restrict__ cb){
  __shared__ float red[4];
  const int n = blockIdx.x;
  const int tid = threadIdx.x;
  float pb = 0.f;
  for (int k = tid; k < 512; k += 256){
    float xw = xW[n*512 + k], hw = hW[n*512 + k];
    xWb[n*512 + k] = f2bf(xw * inw[k]);
    hWb[n*512 + k] = f2bf(hw * hidw[k]);
    pb += hw * hmixb[k];
  }
  #pragma unroll
  for (int off = 1; off < 64; off <<= 1) pb += __shfl_xor(pb, off);
  if ((tid & 63) == 0) red[tid >> 6] = pb;
  __syncthreads();
  if (tid == 0){
    float dot = red[0] + red[1] + red[2] + red[3];
    if (n < 1024){ cb[n] = xb[n] + hb[n] + dot; }
    else         { cb[n] = xb[n]; cb[n + 512] = hb[n] + dot; }
  }
}

// =====================================================================
// wbuild (validated)
// =====================================================================
extern "C" __global__ void __launch_bounds__(256)
wbuild(const float* __restrict__ x, const float* __restrict__ h,
       const float* __restrict__ hmixW,
       u16* __restrict__ Ax, u16* __restrict__ Ahm)
{
  __shared__ float tile[32][264];
  __shared__ float invx_s[256];
  __shared__ float invh_s[258];
  __shared__ float hmw_s[1536];

  const int b = blockIdx.y, fc = blockIdx.x;
  const int f0 = fc*256;
  const int t = threadIdx.x;
  const int r = t >> 3, q = t & 7;

  for (int i = t; i < 1536; i += 256) hmw_s[i] = hmixW[i];

  float ssq = 0.f;
  for (int cc = 0; cc < 16; ++cc){
    __syncthreads();
    const float* src = x + ((size_t)(b*512 + cc*32 + r))*1024 + f0;
    #pragma unroll
    for (int i = 0; i < 8; ++i)
      *(f32x4*)&tile[r][q*4 + i*32] = *(const f32x4*)(src + q*4 + i*32);
    __syncthreads();
    float p = 0.f;
    #pragma unroll
    for (int rr = 0; rr < 32; ++rr){ float v = tile[rr][t]; p += v*v; }
    ssq += p;
  }
  invx_s[t] = rsqrtf(ssq*(1.f/512.f) + EPSV);
  for (int cc = 0; cc < 16; ++cc){
    __syncthreads();
    const float* src = x + ((size_t)(b*512 + cc*32 + r))*1024 + f0;
    #pragma unroll
    for (int i = 0; i < 8; ++i)
      *(f32x4*)&tile[r][q*4 + i*32] = *(const f32x4*)(src + q*4 + i*32);
    __syncthreads();
    #pragma unroll
    for (int it = 0; it < 4; ++it){
      int id = it*256 + t;
      int pix = id >> 2, c8 = (id & 3)*8;
      float iv = invx_s[pix];
      short8 pk;
      #pragma unroll
      for (int j = 0; j < 8; ++j) pk[j] = (short)f2bf(tile[c8+j][pix]*iv);
      *(short8*)(Ax + ((size_t)(b*1024 + f0 + pix))*512 + cc*32 + c8) = pk;
    }
  }
  float ssqh = 0.f, ssqL = 0.f, ssqR = 0.f;
  for (int cc = 0; cc < 16; ++cc){
    __syncthreads();
    const float* src = h + ((size_t)(b*512 + cc*32 + r))*1024 + f0;
    #pragma unroll
    for (int i = 0; i < 8; ++i)
      *(f32x4*)&tile[r][q*4 + i*32] = *(const f32x4*)(src + q*4 + i*32);
    if (t < 32){
      tile[t][256] = (f0 > 0) ? h[((size_t)(b*512 + cc*32 + t))*1024 + f0 - 1] : 0.f;
    } else if (t < 64){
      int rr = t - 32;
      tile[rr][257] = (f0 + 256 < 1024) ? h[((size_t)(b*512 + cc*32 + rr))*1024 + f0 + 256] : 0.f;
    }
    __syncthreads();
    float p = 0.f;
    #pragma unroll
    for (int rr = 0; rr < 32; ++rr){ float v = tile[rr][t]; p += v*v; }
    ssqh += p;
    if (t == 0){ float p2=0.f; for (int rr=0; rr<32; ++rr){ float v=tile[rr][256]; p2+=v*v; } ssqL += p2; }
    if (t == 1){ float p2=0.f; for (int rr=0; rr<32; ++rr){ float v=tile[rr][257]; p2+=v*v; } ssqR += p2; }
  }
  invh_s[1 + t] = rsqrtf(ssqh*(1.f/512.f) + EPSV);
  if (t == 0) invh_s[0]   = rsqrtf(ssqL*(1.f/512.f) + EPSV);
  if (t == 1) invh_s[257] = rsqrtf(ssqR*(1.f/512.f) + EPSV);
  for (int cc = 0; cc < 16; ++cc){
    __syncthreads();
    const float* src = h + ((size_t)(b*512 + cc*32 + r))*1024 + f0;
    #pragma unroll
    for (int i = 0; i < 8; ++i)
      *(f32x4*)&tile[r][q*4 + i*32] = *(const f32x4*)(src + q*4 + i*32);
    if (t < 32){
      tile[t][256] = (f0 > 0) ? h[((size_t)(b*512 + cc*32 + t))*1024 + f0 - 1] : 0.f;
    } else if (t < 64){
      int rr = t - 32;
      tile[rr][257] = (f0 + 256 < 1024) ? h[((size_t)(b*512 + cc*32 + rr))*1024 + f0 + 256] : 0.f;
    }
    __syncthreads();
    #pragma unroll
    for (int it = 0; it < 4; ++it){
      int id = it*256 + t;
      int pix = id >> 2, c8 = (id & 3)*8;
      int colL = (pix == 0)   ? 256 : (pix - 1);
      int colR = (pix == 255) ? 257 : (pix + 1);
      float iL = invh_s[pix], iC = invh_s[pix+1], iR = invh_s[pix+2];
      short8 pk;
      #pragma unroll
      for (int j = 0; j < 8; ++j){
        int c = c8 + j;
        int cg = cc*32 + c;
        float v = hmw_s[cg*3+0]*tile[c][colL]*iL
                + hmw_s[cg*3+1]*tile[c][pix ]*iC
                + hmw_s[cg*3+2]*tile[c][colR]*iR;
        pk[j] = (short)f2bf(v);
      }
      *(short8*)(Ahm + ((size_t)(b*1024 + f0 + pix))*512 + cc*32 + c8) = pk;
    }
  }
}

// =====================================================================
// gemm_gates v4: 256 pixels x 32 channels, 4 waves, 1 block/CU.
//  - B: FRAGMENT-MAJOR panel — 96 fragments x 1KB, each contiguous
//    (lane l at l*16): conflict-free ds_read_b128, immediate offsets.
//  - A: wave-private tri-buffered DMA; per-wave counted vmcnt(4),
//    no in-loop barriers.
// =====================================================================
extern "C" __global__ void __launch_bounds__(256, 1)
gemm_gates(const float* __restrict__ x, const float* __restrict__ h,
           const u16* __restrict__ Abase,   // d_out: A_x then A_hm, each 65536x512
           const u16* __restrict__ xWb, const u16* __restrict__ hWb,
           const float* __restrict__ cb,
           float* __restrict__ ssqp, u16* __restrict__ sbf)
{
  extern __shared__ __align__(16) char smem[];  // 147456
  const int t = threadIdx.x;
  const int bid = blockIdx.x;
  const int swz = (bid & 7)*512 + (bid >> 3);       // XCD swizzle, bijective
  const int mh = swz >> 4, ch = swz & 15;
  const int b = mh >> 2, f0 = (mh & 3)*256;
  const int c0 = ch*32;
  const int pixbase = b*1024 + f0;
  const int w = t >> 6, lane = t & 63, li = lane & 15, lg = lane >> 4;

  char* Bbase = smem + 49152;

  // per-thread A staging geometry: wave w stages slots u = w*256 + uu*64 + lane
  int rrA[4], kqA[4];
  #pragma unroll
  for (int uu = 0; uu < 4; ++uu){
    int u = w*256 + uu*64 + lane;
    rrA[uu] = ((u >> 5) & 7)*8 + (u & 7) + w*64;   // global pixel row in block
    kqA[uu] = (u >> 3) & 3;
  }

  // B fragment-major: fragment fi = kk*6 + g*2 + ct  (fi 0..95), 1KB each,
  // lane (li,lg) holds W[(g*512 + c0 + ct*16 + li)*512 + kk*32 + lg*8 .. +8]
  auto stageB = [&](const u16* Wsrc){
    #pragma unroll
    for (int i = 0; i < 24; ++i){
      int fi = i*4 + w;                  // wave-uniform fragment index
      int kk = fi / 6, rem = fi - kk*6;
      int g = rem >> 1, ct = rem & 1;
      const u16* src = Wsrc + ((size_t)(g*512 + c0 + ct*16 + li))*512 + kk*32 + lg*8;
      gload_lds16(src, Bbase + fi*1024);   // dest wave-dependent via fi
    }
  };
  auto stageA = [&](const u16* Asrc, int kk, int buf){
    char* adst = smem + buf*16384 + w*4096;
    #pragma unroll
    for (int uu = 0; uu < 4; ++uu){
      gload_lds16(Asrc + ((size_t)(pixbase + rrA[uu]))*512 + kk*32 + kqA[uu]*8,
                  adst + uu*1024);
    }
  };

  f32x4 accr[2][4] = {}, accz[2][4] = {}, accg1[2][4] = {}, accg2[2][4] = {};

  auto kstep = [&](int kk, int buf, f32x4 (&accg)[2][4]){
    const char* ab = smem + buf*16384 + w*4096;
    short8 af[4];
    #pragma unroll
    for (int mf = 0; mf < 4; ++mf){
      int rl = mf*16 + li;                          // local row in wave slice
      af[mf] = *(const short8*)(ab + ((rl >> 3) << 9) + (lg << 7) + ((rl & 7) << 4));
    }
    #pragma unroll
    for (int ct = 0; ct < 2; ++ct){
      const char* bb = Bbase + (kk*6 + ct)*1024 + lane*16;
      short8 bf0 = *(const short8*)(bb);            // g=0
      short8 bf1 = *(const short8*)(bb + 2048);     // g=1
      short8 bf2 = *(const short8*)(bb + 4096);     // g=2
      #pragma unroll
      for (int mf = 0; mf < 4; ++mf){
        accr[ct][mf] = __builtin_amdgcn_mfma_f32_16x16x32_bf16(af[mf], bf0, accr[ct][mf], 0,0,0);
        accz[ct][mf] = __builtin_amdgcn_mfma_f32_16x16x32_bf16(af[mf], bf1, accz[ct][mf], 0,0,0);
        accg[ct][mf] = __builtin_amdgcn_mfma_f32_16x16x32_bf16(af[mf], bf2, accg[ct][mf], 0,0,0);
      }
    }
  };

  // ================= phase 0 (x-side) =================
  stageB(xWb);
  stageA(Abase, 0, 0);
  stageA(Abase, 1, 1);
  __syncthreads();                                   // drains all staging
  #pragma unroll
  for (int j = 0; j < 16; ++j){
    if (j < 14) stageA(Abase, j + 2, (j + 2) % 3);
    kstep(j, j % 3, accg1);
    if (j < 14)      { asm volatile("s_waitcnt vmcnt(4)" ::: "memory"); }
    else if (j == 14){ asm volatile("s_waitcnt vmcnt(0)" ::: "memory"); }
    __builtin_amdgcn_sched_barrier(0);
  }
  __syncthreads();                                   // phase-0 B reads done
  // ================= phase 1 (h-side) =================
  const u16* A1 = Abase + 33554432;
  stageB(hWb);
  stageA(A1, 0, 0);
  stageA(A1, 1, 1);
  __syncthreads();
  #pragma unroll
  for (int j = 0; j < 16; ++j){
    if (j < 14) stageA(A1, j + 2, (j + 2) % 3);
    kstep(j, j % 3, accg2);
    if (j < 14)      { asm volatile("s_waitcnt vmcnt(4)" ::: "memory"); }
    else if (j == 14){ asm volatile("s_waitcnt vmcnt(0)" ::: "memory"); }
    __builtin_amdgcn_sched_barrier(0);
  }
  __syncthreads();                                   // safe to reuse LDS

  // ---------------- epilogue: gates, h_new, s ----------------
  float (*stg)[264] = (float(*)[264])smem;   // [32][264] f32
  float ps[4][4] = {};
  #pragma unroll
  for (int ct = 0; ct < 2; ++ct){
    const int c = c0 + ct*16 + li;
    const float cbr = cb[c], cbz = cb[512 + c], xbn = cb[1024 + c], hbn = cb[1536 + c];
    #pragma unroll
    for (int mf = 0; mf < 4; ++mf){
      const int f = f0 + w*64 + mf*16 + lg*4;
      const size_t gidx = ((size_t)(b*512 + c))*1024 + f;
      f32x4 hp = *(const f32x4*)(h + gidx);
      f32x4 xt = *(const f32x4*)(x + gidx);
      f32x4 sv;
      #pragma unroll
      for (int j = 0; j < 4; ++j){
        float rr = sigm(accr[ct][mf][j] + cbr);
        float zz = sigm(accz[ct][mf][j] + cbz);
        float g  = accg1[ct][mf][j] + xbn + rr*(accg2[ct][mf][j] + hbn);
        float th = tanh_fast(g);
        float s  = (1.f - zz)*th + zz*hp[j] + xt[j];
        sv[j] = s;
        ps[mf][j] += s*s;
      }
      *(f32x4*)&stg[ct*16 + li][w*64 + mf*16 + lg*4] = sv;
    }
  }
  #pragma unroll
  for (int off = 1; off < 16; off <<= 1)
    #pragma unroll
    for (int mf = 0; mf < 4; ++mf)
      #pragma unroll
      for (int j = 0; j < 4; ++j)
        ps[mf][j] += __shfl_xor(ps[mf][j], off);
  if (li == 0){
    #pragma unroll
    for (int mf = 0; mf < 4; ++mf){
      f32x4 v; v[0]=ps[mf][0]; v[1]=ps[mf][1]; v[2]=ps[mf][2]; v[3]=ps[mf][3];
      *(f32x4*)(ssqp + (size_t)ch*65536 + pixbase + w*64 + mf*16 + lg*4) = v;
    }
  }
  __syncthreads();
  {
    const int cl = t >> 3, seg = t & 7;
    u16* dst = sbf + ((size_t)(b*512 + c0 + cl))*1024 + f0 + seg*32;
    #pragma unroll
    for (int qq = 0; qq < 2; ++qq){
      f32x4 a0 = *(const f32x4*)&stg[cl][seg*32 + qq*16 + 0];
      f32x4 a1 = *(const f32x4*)&stg[cl][seg*32 + qq*16 + 4];
      f32x4 a2 = *(const f32x4*)&stg[cl][seg*32 + qq*16 + 8];
      f32x4 a3 = *(const f32x4*)&stg[cl][seg*32 + qq*16 + 12];
      short8 p0, p1;
      #pragma unroll
      for (int j = 0; j < 4; ++j){
        p0[j]   = (short)f2bf(a0[j]); p0[j+4] = (short)f2bf(a1[j]);
        p1[j]   = (short)f2bf(a2[j]); p1[j+4] = (short)f2bf(a3[j]);
      }
      *(short8*)(dst + qq*16)     = p0;
      *(short8*)(dst + qq*16 + 8) = p1;
    }
  }
}

// =====================================================================
// outnorm (validated)
// =====================================================================
extern "C" __global__ void __launch_bounds__(256)
outnorm(const float* __restrict__ ssqp, const u16* __restrict__ sbf,
        const float* __restrict__ outw, float* __restrict__ out)
{
  __shared__ float invf[1024];
  const int b = blockIdx.y, cch = blockIdx.x;
  const int t = threadIdx.x;
  f32x4 acc = {};
  #pragma unroll
  for (int p = 0; p < 16; ++p){
    f32x4 v = *(const f32x4*)(ssqp + (size_t)p*65536 + b*1024 + t*4);
    acc[0]+=v[0]; acc[1]+=v[1]; acc[2]+=v[2]; acc[3]+=v[3];
  }
  f32x4 iv;
  #pragma unroll
  for (int j = 0; j < 4; ++j) iv[j] = rsqrtf(acc[j]*(1.f/512.f) + EPSV);
  *(f32x4*)&invf[t*4] = iv;
  __syncthreads();
  for (int cl = 0; cl < 32; ++cl){
    const int c = cch*32 + cl;
    const float ow = outw[c];
    const u16* row = sbf + ((size_t)(b*512 + c))*1024;
    u16x4 sv = *(const u16x4*)(row + t*4);
    f32x4 o;
    #pragma unroll
    for (int j = 0; j < 4; ++j) o[j] = bf2f(sv[j]) * invf[t*4 + j] * ow;
    *(f32x4*)(out + ((size_t)(b*512 + c))*1024 + t*4) = o;
  }
}

// =====================================================================
// ================ FALLBACK (round-1, validated) ======================
// =====================================================================
#define FB_AXN_OFF 0
#define FB_AHM_OFF 32768
#define FB_RAW_OFF 65536
#define FB_PART_OFF 102400
#define FB_INVX_OFF 104512
#define FB_INVH_OFF 104640
#define FB_SSQ2_OFF 104784
#define FB_INVO_OFF 105936
#define FB_SMEM_BYTES 106112

extern "C" __global__ void fb_wconv(const float* __restrict__ xW, const float* __restrict__ hW,
                                    u16* __restrict__ xWb, u16* __restrict__ hWb){
  int i = blockIdx.x*256 + threadIdx.x;
  xWb[i] = f2bf(xW[i]);
  hWb[i] = f2bf(hW[i]);
}

extern "C" __global__ void __launch_bounds__(512, 2)
fb_gru(const float* __restrict__ x, const float* __restrict__ h,
       const float* __restrict__ inw, const float* __restrict__ hidw,
       const float* __restrict__ outw,
       const float* __restrict__ xb, const float* __restrict__ hmixWc,
       const float* __restrict__ hmixb, const float* __restrict__ hb,
       const u16* __restrict__ xWb, const u16* __restrict__ hWb,
       float* __restrict__ out)
{
  extern __shared__ __align__(16) char smem[];
  const int b  = blockIdx.y;
  const int f0 = blockIdx.x * 32;
  const int t  = threadIdx.x;
  u16* raw = (u16*)(smem + FB_RAW_OFF);
  float* part = (float*)(smem + FB_PART_OFF);
  {
    const int fq = t & 7, cb2 = t >> 3;
    #pragma unroll
    for (int pass = 0; pass < 8; ++pass){
      int c = pass*64 + cb2;
      f32x4 v = *(const f32x4*)(x + ((size_t)(b*512 + c))*1024 + f0 + fq*4);
      u16* d = raw + c*36 + fq*4;
      d[0] = f2bf(v[0]); d[1] = f2bf(v[1]); d[2] = f2bf(v[2]); d[3] = f2bf(v[3]);
    }
  }
  __syncthreads();
  {
    const int f = t & 31, cs = t >> 5;
    float p = 0.f;
    for (int i = 0; i < 32; ++i){ float v = bf2f(raw[(cs*32 + i)*36 + f]); p += v*v; }
    part[cs*33 + f] = p;
  }
  __syncthreads();
  if (t < 32){
    float s = 0.f;
    for (int i = 0; i < 16; ++i) s += part[i*33 + t];
    ((float*)(smem + FB_INVX_OFF))[t] = rsqrtf(s*(1.f/512.f) + EPSV);
  }
  __syncthreads();
  {
    const int f = t >> 4, cc = t & 15;
    const float iv = ((float*)(smem + FB_INVX_OFF))[f];
    #pragma unroll
    for (int it = 0; it < 4; ++it){
      int cbase = (cc + it*16)*8;
      short8 pk;
      #pragma unroll
      for (int j = 0; j < 8; ++j){
        float v = bf2f(raw[(cbase+j)*36 + f]) * iv * inw[cbase+j];
        pk[j] = (short)f2bf(v);
      }
      *(short8*)(smem + FB_AXN_OFF + f*1024 + ((cbase*2) ^ ((f&7)<<4))) = pk;
    }
  }
  __syncthreads();
  {
    const int fq = t & 7, cb2 = t >> 3;
    #pragma unroll
    for (int pass = 0; pass < 8; ++pass){
      int c = pass*64 + cb2;
      f32x4 v = *(const f32x4*)(h + ((size_t)(b*512 + c))*1024 + f0 + fq*4);
      u16* d = raw + c*36 + 1 + fq*4;
      d[0] = f2bf(v[0]); d[1] = f2bf(v[1]); d[2] = f2bf(v[2]); d[3] = f2bf(v[3]);
    }
    {
      int c = t;
      size_t base = ((size_t)(b*512 + c))*1024;
      float lv = (f0 > 0)          ? h[base + f0 - 1]  : 0.f;
      float rv = (f0 + 32 < 1024)  ? h[base + f0 + 32] : 0.f;
      raw[c*36 + 0]  = f2bf(lv);
      raw[c*36 + 33] = f2bf(rv);
    }
  }
  __syncthreads();
  {
    const int fw = t & 63, cs = t >> 6;
    if (fw < 34){
      float p = 0.f;
      for (int i = 0; i < 64; ++i){ float v = bf2f(raw[(cs*64 + i)*36 + fw]); p += v*v; }
      part[cs*35 + fw] = p;
    }
  }
  __syncthreads();
  if (t < 34){
    float s = 0.f;
    for (int i = 0; i < 8; ++i) s += part[i*35 + t];
    ((float*)(smem + FB_INVH_OFF))[t] = rsqrtf(s*(1.f/512.f) + EPSV);
  }
  __syncthreads();
  {
    const int fr = t >> 5, cc = t & 31;
    const float* invh = (const float*)(smem + FB_INVH_OFF);
    const float iL = invh[fr], iC = invh[fr + 1], iR = invh[fr + 2];
    #pragma unroll
    for (int it = 0; it < 2; ++it){
      const int cbase = (cc + it*32)*8;
      short8 o;
      #pragma unroll
      for (int j = 0; j < 8; ++j){
        int c = cbase + j;
        float hL = bf2f(raw[c*36 + fr])     * iL;
        float hC = bf2f(raw[c*36 + fr + 1]) * iC;
        float hR = bf2f(raw[c*36 + fr + 2]) * iR;
        float v = (hmixWc[c*3]*hL + hmixWc[c*3+1]*hC + hmixWc[c*3+2]*hR) * hidw[c] + hmixb[c];
        o[j] = (short)f2bf(v);
      }
      *(short8*)(smem + FB_AHM_OFF + fr*1024 + ((cbase*2) ^ ((fr&7)<<4))) = o;
    }
  }
  __syncthreads();
  const int wv = t >> 6, lane = t & 63, li = lane & 15, lg = lane >> 4;
  const int n0 = wv*64;
  f32x4 ar[2][4] = {}, az[2][4] = {}, axg[2][4] = {}, ahg[2][4] = {};
  #pragma unroll
  for (int src = 0; src < 2; ++src){
    const char* A = smem + (src ? FB_AHM_OFF : FB_AXN_OFF);
    const u16* W = src ? hWb : xWb;
    for (int k0 = 0; k0 < 512; k0 += 32){
      const int kb = (k0*2 + lg*16) ^ ((li & 7) << 4);
      short8 a0 = *(const short8*)(A + li*1024 + kb);
      short8 a1 = *(const short8*)(A + (li+16)*1024 + kb);
      #pragma unroll
      for (int nt = 0; nt < 4; ++nt){
        const u16* bp = W + (size_t)(n0 + nt*16 + li)*512 + k0 + lg*8;
        short8 br = *(const short8*)(bp);
        short8 bz = *(const short8*)(bp + 512*512);
        short8 bg = *(const short8*)(bp + 1024*512);
        ar[0][nt] = __builtin_amdgcn_mfma_f32_16x16x32_bf16(a0, br, ar[0][nt], 0,0,0);
        ar[1][nt] = __builtin_amdgcn_mfma_f32_16x16x32_bf16(a1, br, ar[1][nt], 0,0,0);
        az[0][nt] = __builtin_amdgcn_mfma_f32_16x16x32_bf16(a0, bz, az[0][nt], 0,0,0);
        az[1][nt] = __builtin_amdgcn_mfma_f32_16x16x32_bf16(a1, bz, az[1][nt], 0,0,0);
        if (src == 0){
          axg[0][nt] = __builtin_amdgcn_mfma_f32_16x16x32_bf16(a0, bg, axg[0][nt], 0,0,0);
          axg[1][nt] = __builtin_amdgcn_mfma_f32_16x16x32_bf16(a1, bg, axg[1][nt], 0,0,0);
        } else {
          ahg[0][nt] = __builtin_amdgcn_mfma_f32_16x16x32_bf16(a0, bg, ahg[0][nt], 0,0,0);
          ahg[1][nt] = __builtin_amdgcn_mfma_f32_16x16x32_bf16(a1, bg, ahg[1][nt], 0,0,0);
        }
      }
    }
  }
  float ps[8] = {0,0,0,0,0,0,0,0};
  #pragma unroll
  for (int nt = 0; nt < 4; ++nt){
    const int c = n0 + nt*16 + li;
    const float xbr = xb[c], xbz = xb[512+c], xbg = xb[1024+c];
    const float hbr = hb[c], hbz = hb[512+c], hbg = hb[1024+c];
    #pragma unroll
    for (int mt = 0; mt < 2; ++mt){
      const size_t idx = ((size_t)(b*512 + c))*1024 + f0 + mt*16 + lg*4;
      const f32x4 hp = *(const f32x4*)(h + idx);
      const f32x4 xt = *(const f32x4*)(x + idx);
      f32x4 sv;
      #pragma unroll
      for (int j = 0; j < 4; ++j){
        float rr = sigm(ar[mt][nt][j] + xbr + hbr);
        float zz = sigm(az[mt][nt][j] + xbz + hbz);
        float g  = axg[mt][nt][j] + xbg + rr*(ahg[mt][nt][j] + hbg);
        float th = tanh_fast(g);
        float hv = (1.f - zz)*th + zz*hp[j];
        float s  = hv + xt[j];
        sv[j] = s;
        ps[mt*4 + j] += s*s;
      }
      ar[mt][nt] = sv;
    }
  }
  #pragma unroll
  for (int off = 1; off < 16; off <<= 1){
    #pragma unroll
    for (int p = 0; p < 8; ++p) ps[p] += __shfl_xor(ps[p], off);
  }
  __syncthreads();
  float* stg = (float*)(smem + FB_AXN_OFF);
  #pragma unroll
  for (int nt = 0; nt < 4; ++nt){
    const int n = n0 + nt*16 + li;
    #pragma unroll
    for (int mt = 0; mt < 2; ++mt){
      const int m0 = mt*16 + lg*4;
      *(f32x4*)(stg + n*32 + (m0 ^ ((n & 7) << 2))) = ar[mt][nt];
    }
  }
  float* sq2 = (float*)(smem + FB_SSQ2_OFF);
  if (li == 0){
    #pragma unroll
    for (int p = 0; p < 8; ++p){
      int m = (p >> 2)*16 + lg*4 + (p & 3);
      sq2[m*9 + wv] = ps[p];
    }
  }
  __syncthreads();
  if (t < 32){
    float s = 0.f;
    for (int i = 0; i < 8; ++i) s += sq2[t*9 + i];
    ((float*)(smem + FB_INVO_OFF))[t] = rsqrtf(s*(1.f/512.f) + EPSV);
  }
  __syncthreads();
  {
    const float* invO = (const float*)(smem + FB_INVO_OFF);
    const int cb2 = t >> 3, chh = t & 7;
    #pragma unroll
    for (int pass = 0; pass < 8; ++pass){
      int c = pass*64 + cb2;
      int base = (chh*4) ^ ((c & 7) << 2);
      f32x4 v = *(const f32x4*)(stg + c*32 + base);
      float ow = outw[c];
      f32x4 o;
      #pragma unroll
      for (int j = 0; j < 4; ++j) o[j] = v[j] * invO[chh*4 + j] * ow;
      *(f32x4*)(out + ((size_t)(b*512 + c))*1024 + f0 + chh*4) = o;
    }
  }
}

// =====================================================================
extern "C" void kernel_launch(void* const* d_in, const int* in_sizes, int n_in,
                              void* d_out, int out_size, void* d_ws, size_t ws_size,
                              hipStream_t stream){
  (void)in_sizes; (void)n_in; (void)out_size;
  const float* x      = (const float*)d_in[0];
  const float* h      = (const float*)d_in[1];
  const float* inw    = (const float*)d_in[2];
  const float* hidw   = (const float*)d_in[3];
  const float* outw   = (const float*)d_in[4];
  const float* xW     = (const float*)d_in[5];
  const float* xb     = (const float*)d_in[6];
  const float* hmixW  = (const float*)d_in[7];
  const float* hmixb  = (const float*)d_in[8];
  const float* hW     = (const float*)d_in[9];
  const float* hb     = (const float*)d_in[10];

  if (ws_size >= (size_t)WS_NEED){
    u16*   xWb  = (u16*)((char*)d_ws + WS_WXB);
    u16*   hWb  = (u16*)((char*)d_ws + WS_WHB);
    float* cbw  = (float*)((char*)d_ws + WS_CB);
    float* ssqp = (float*)((char*)d_ws + WS_SSQP);
    u16*   sbf  = (u16*)((char*)d_ws + WS_SBF);
    u16*   Ax   = (u16*)d_out;                    // A_x [65536][512]

    hipFuncSetAttribute(reinterpret_cast<const void*>(gemm_gates),
                        hipFuncAttributeMaxDynamicSharedMemorySize, GG_SMEM);

    wprep<<<1536, 256, 0, stream>>>(xW, hW, inw, hidw, xb, hmixb, hb, xWb, hWb, cbw);
    wbuild<<<dim3(4, 64), 256, 0, stream>>>(x, h, hmixW, Ax, Ax + 33554432);
    gemm_gates<<<4096, 256, GG_SMEM, stream>>>(x, h, Ax, xWb, hWb, cbw, ssqp, sbf);
    outnorm<<<dim3(16, 64), 256, 0, stream>>>(ssqp, sbf, outw, (float*)d_out);
  } else {
    u16* xWb = (u16*)d_ws;
    u16* hWb = xWb + 786432;
    hipFuncSetAttribute(reinterpret_cast<const void*>(fb_gru),
                        hipFuncAttributeMaxDynamicSharedMemorySize, FB_SMEM_BYTES);
    fb_wconv<<<3072, 256, 0, stream>>>(xW, hW, xWb, hWb);
    dim3 grid(32, 64);
    fb_gru<<<grid, 512, FB_SMEM_BYTES, stream>>>(x, h, inw, hidw, outw,
                                                 xb, hmixW, hmixb, hb,
                                                 xWb, hWb, (float*)d_out);
  }
}

// Round 10
// 614.488 us; speedup vs baseline: 1.1612x; 1.1612x over previous
//
#include <hip/hip_runtime.h>

typedef __attribute__((ext_vector_type(8))) short short8;
typedef __attribute__((ext_vector_type(4))) float f32x4;
typedef __attribute__((ext_vector_type(4))) unsigned short u16x4;
typedef unsigned short u16;
typedef unsigned int u32;

#define EPSV 1e-6f

__device__ __forceinline__ u16 f2bf(float f){
  u32 u = __float_as_uint(f);
  u = u + 0x7fffu + ((u >> 16) & 1u);
  return (u16)(u >> 16);
}
__device__ __forceinline__ float bf2f(u16 h){
  return __uint_as_float(((u32)h) << 16);
}
__device__ __forceinline__ float sigm(float v){ return 1.f/(1.f + __expf(-v)); }
__device__ __forceinline__ float tanh_fast(float g){
  float e = __expf(-2.f*fabsf(g));
  return copysignf((1.f - e)/(1.f + e), g);
}
__device__ __forceinline__ void gload_lds16(const void* g, void* l){
  __builtin_amdgcn_global_load_lds(
      (const __attribute__((address_space(1))) u32*)g,
      (__attribute__((address_space(3))) u32*)l, 16, 0, 0);
}

// ---------------- ws layout (main path) ----------------
#define WS_WXB   0u           // 1536*512 u16
#define WS_WHB   1572864u
#define WS_CB    3145728u     // 2048 f32
#define WS_SSQP  3153920u     // 16*65536 f32
#define WS_SBF   7348224u     // 65536*512 u16
#define WS_NEED  74457088u

#define GG_SMEM  163840       // A dbuf 2*32768 (frag-major, per-wave) + B panel 98304 (frag-major)

// =====================================================================
// wprep (validated)
// =====================================================================
extern "C" __global__ void wprep(const float* __restrict__ xW, const float* __restrict__ hW,
                                 const float* __restrict__ inw, const float* __restrict__ hidw,
                                 const float* __restrict__ xb, const float* __restrict__ hmixb,
                                 const float* __restrict__ hb,
                                 u16* __restrict__ xWb, u16* __restrict__ hWb,
                                 float* __restrict__ cb){
  __shared__ float red[4];
  const int n = blockIdx.x;
  const int tid = threadIdx.x;
  float pb = 0.f;
  for (int k = tid; k < 512; k += 256){
    float xw = xW[n*512 + k], hw = hW[n*512 + k];
    xWb[n*512 + k] = f2bf(xw * inw[k]);
    hWb[n*512 + k] = f2bf(hw * hidw[k]);
    pb += hw * hmixb[k];
  }
  #pragma unroll
  for (int off = 1; off < 64; off <<= 1) pb += __shfl_xor(pb, off);
  if ((tid & 63) == 0) red[tid >> 6] = pb;
  __syncthreads();
  if (tid == 0){
    float dot = red[0] + red[1] + red[2] + red[3];
    if (n < 1024){ cb[n] = xb[n] + hb[n] + dot; }
    else         { cb[n] = xb[n]; cb[n + 512] = hb[n] + dot; }
  }
}

// =====================================================================
// wbuild (validated)
// =====================================================================
extern "C" __global__ void __launch_bounds__(256)
wbuild(const float* __restrict__ x, const float* __restrict__ h,
       const float* __restrict__ hmixW,
       u16* __restrict__ Ax, u16* __restrict__ Ahm)
{
  __shared__ float tile[32][264];
  __shared__ float invx_s[256];
  __shared__ float invh_s[258];
  __shared__ float hmw_s[1536];

  const int b = blockIdx.y, fc = blockIdx.x;
  const int f0 = fc*256;
  const int t = threadIdx.x;
  const int r = t >> 3, q = t & 7;

  for (int i = t; i < 1536; i += 256) hmw_s[i] = hmixW[i];

  float ssq = 0.f;
  for (int cc = 0; cc < 16; ++cc){
    __syncthreads();
    const float* src = x + ((size_t)(b*512 + cc*32 + r))*1024 + f0;
    #pragma unroll
    for (int i = 0; i < 8; ++i)
      *(f32x4*)&tile[r][q*4 + i*32] = *(const f32x4*)(src + q*4 + i*32);
    __syncthreads();
    float p = 0.f;
    #pragma unroll
    for (int rr = 0; rr < 32; ++rr){ float v = tile[rr][t]; p += v*v; }
    ssq += p;
  }
  invx_s[t] = rsqrtf(ssq*(1.f/512.f) + EPSV);
  for (int cc = 0; cc < 16; ++cc){
    __syncthreads();
    const float* src = x + ((size_t)(b*512 + cc*32 + r))*1024 + f0;
    #pragma unroll
    for (int i = 0; i < 8; ++i)
      *(f32x4*)&tile[r][q*4 + i*32] = *(const f32x4*)(src + q*4 + i*32);
    __syncthreads();
    #pragma unroll
    for (int it = 0; it < 4; ++it){
      int id = it*256 + t;
      int pix = id >> 2, c8 = (id & 3)*8;
      float iv = invx_s[pix];
      short8 pk;
      #pragma unroll
      for (int j = 0; j < 8; ++j) pk[j] = (short)f2bf(tile[c8+j][pix]*iv);
      *(short8*)(Ax + ((size_t)(b*1024 + f0 + pix))*512 + cc*32 + c8) = pk;
    }
  }
  float ssqh = 0.f, ssqL = 0.f, ssqR = 0.f;
  for (int cc = 0; cc < 16; ++cc){
    __syncthreads();
    const float* src = h + ((size_t)(b*512 + cc*32 + r))*1024 + f0;
    #pragma unroll
    for (int i = 0; i < 8; ++i)
      *(f32x4*)&tile[r][q*4 + i*32] = *(const f32x4*)(src + q*4 + i*32);
    if (t < 32){
      tile[t][256] = (f0 > 0) ? h[((size_t)(b*512 + cc*32 + t))*1024 + f0 - 1] : 0.f;
    } else if (t < 64){
      int rr = t - 32;
      tile[rr][257] = (f0 + 256 < 1024) ? h[((size_t)(b*512 + cc*32 + rr))*1024 + f0 + 256] : 0.f;
    }
    __syncthreads();
    float p = 0.f;
    #pragma unroll
    for (int rr = 0; rr < 32; ++rr){ float v = tile[rr][t]; p += v*v; }
    ssqh += p;
    if (t == 0){ float p2=0.f; for (int rr=0; rr<32; ++rr){ float v=tile[rr][256]; p2+=v*v; } ssqL += p2; }
    if (t == 1){ float p2=0.f; for (int rr=0; rr<32; ++rr){ float v=tile[rr][257]; p2+=v*v; } ssqR += p2; }
  }
  invh_s[1 + t] = rsqrtf(ssqh*(1.f/512.f) + EPSV);
  if (t == 0) invh_s[0]   = rsqrtf(ssqL*(1.f/512.f) + EPSV);
  if (t == 1) invh_s[257] = rsqrtf(ssqR*(1.f/512.f) + EPSV);
  for (int cc = 0; cc < 16; ++cc){
    __syncthreads();
    const float* src = h + ((size_t)(b*512 + cc*32 + r))*1024 + f0;
    #pragma unroll
    for (int i = 0; i < 8; ++i)
      *(f32x4*)&tile[r][q*4 + i*32] = *(const f32x4*)(src + q*4 + i*32);
    if (t < 32){
      tile[t][256] = (f0 > 0) ? h[((size_t)(b*512 + cc*32 + t))*1024 + f0 - 1] : 0.f;
    } else if (t < 64){
      int rr = t - 32;
      tile[rr][257] = (f0 + 256 < 1024) ? h[((size_t)(b*512 + cc*32 + rr))*1024 + f0 + 256] : 0.f;
    }
    __syncthreads();
    #pragma unroll
    for (int it = 0; it < 4; ++it){
      int id = it*256 + t;
      int pix = id >> 2, c8 = (id & 3)*8;
      int colL = (pix == 0)   ? 256 : (pix - 1);
      int colR = (pix == 255) ? 257 : (pix + 1);
      float iL = invh_s[pix], iC = invh_s[pix+1], iR = invh_s[pix+2];
      short8 pk;
      #pragma unroll
      for (int j = 0; j < 8; ++j){
        int c = c8 + j;
        int cg = cc*32 + c;
        float v = hmw_s[cg*3+0]*tile[c][colL]*iL
                + hmw_s[cg*3+1]*tile[c][pix ]*iC
                + hmw_s[cg*3+2]*tile[c][colR]*iR;
        pk[j] = (short)f2bf(v);
      }
      *(short8*)(Ahm + ((size_t)(b*1024 + f0 + pix))*512 + cc*32 + c8) = pk;
    }
  }
}

// =====================================================================
// gemm_gates v5: 512 pixels x 32 channels, 8 waves (2/SIMD), 1 block/CU.
//  - B: fragment-major 96x1KB panel resident per phase (prologue-staged).
//  - A: fragment-major per-wave slices, double-buffered, per-wave
//    vmcnt(0) at kstep end; NO in-loop barriers.
// =====================================================================
extern "C" __global__ void __launch_bounds__(512, 2)
gemm_gates(const float* __restrict__ x, const float* __restrict__ h,
           const u16* __restrict__ Abase,   // d_out: A_x then A_hm, each 65536x512
           const u16* __restrict__ xWb, const u16* __restrict__ hWb,
           const float* __restrict__ cb,
           float* __restrict__ ssqp, u16* __restrict__ sbf)
{
  extern __shared__ __align__(16) char smem[];  // 163840
  const int t = threadIdx.x;
  const int bid = blockIdx.x;
  const int swz = (bid & 7)*256 + (bid >> 3);       // XCD swizzle, 2048%8==0 bijective
  const int mh = swz >> 4, ch = swz & 15;
  const int b = mh >> 1, f0 = (mh & 1)*512;
  const int c0 = ch*32;
  const int pixbase = b*1024 + f0;
  const int w = t >> 6, lane = t & 63, li = lane & 15, lg = lane >> 4;

  char* Bbase = smem + 65536;

  // B fragment-major: fi = kk*6 + g*2 + ct (0..95), 1KB each; lane(li,lg)
  // holds W[(g*512 + c0 + ct*16 + li)*512 + kk*32 + lg*8 ..+8]
  auto stageB = [&](const u16* Wsrc){
    #pragma unroll
    for (int i = 0; i < 12; ++i){
      int fi = i*8 + w;                   // wave-dependent dest (round-7 lesson)
      int kk = fi / 6, rem = fi - kk*6;
      int g = rem >> 1, ct = rem & 1;
      gload_lds16(Wsrc + ((size_t)(g*512 + c0 + ct*16 + li))*512 + kk*32 + lg*8,
                  Bbase + fi*1024);
    }
  };
  // A fragment-major: wave w owns pixels w*64..+63; frag (mf) 1KB
  auto stageA = [&](const u16* Asrc, int kk, int buf){
    char* adst = smem + buf*32768 + w*4096;
    #pragma unroll
    for (int mf = 0; mf < 4; ++mf){
      gload_lds16(Asrc + ((size_t)(pixbase + w*64 + mf*16 + li))*512 + kk*32 + lg*8,
                  adst + mf*1024);
    }
  };

  f32x4 accr[2][4] = {}, accz[2][4] = {}, accg1[2][4] = {}, accg2[2][4] = {};

  auto kstep = [&](int kk, int buf, f32x4 (&accg)[2][4]){
    const char* ab = smem + buf*32768 + w*4096;
    short8 af[4];
    #pragma unroll
    for (int mf = 0; mf < 4; ++mf)
      af[mf] = *(const short8*)(ab + mf*1024 + lane*16);
    #pragma unroll
    for (int ct = 0; ct < 2; ++ct){
      const char* bb = Bbase + (kk*6 + ct)*1024 + lane*16;
      short8 bf0 = *(const short8*)(bb);            // g=0 (r)
      short8 bf1 = *(const short8*)(bb + 2048);     // g=1 (z)
      short8 bf2 = *(const short8*)(bb + 4096);     // g=2 (n)
      #pragma unroll
      for (int mf = 0; mf < 4; ++mf){
        accr[ct][mf] = __builtin_amdgcn_mfma_f32_16x16x32_bf16(af[mf], bf0, accr[ct][mf], 0,0,0);
        accz[ct][mf] = __builtin_amdgcn_mfma_f32_16x16x32_bf16(af[mf], bf1, accz[ct][mf], 0,0,0);
        accg[ct][mf] = __builtin_amdgcn_mfma_f32_16x16x32_bf16(af[mf], bf2, accg[ct][mf], 0,0,0);
      }
    }
  };

  // ================= phase 0 (x-side) =================
  stageB(xWb);
  stageA(Abase, 0, 0);
  __syncthreads();                                   // drains all staging
  #pragma unroll
  for (int j = 0; j < 16; ++j){
    if (j < 15) stageA(Abase, j + 1, (j + 1) & 1);
    kstep(j, j & 1, accg1);
    if (j < 15){ asm volatile("s_waitcnt vmcnt(0)" ::: "memory"); }
    __builtin_amdgcn_sched_barrier(0);
  }
  __syncthreads();                                   // phase-0 B reads done
  // ================= phase 1 (h-side) =================
  const u16* A1 = Abase + 33554432;
  stageB(hWb);
  stageA(A1, 0, 0);
  __syncthreads();
  #pragma unroll
  for (int j = 0; j < 16; ++j){
    if (j < 15) stageA(A1, j + 1, (j + 1) & 1);
    kstep(j, j & 1, accg2);
    if (j < 15){ asm volatile("s_waitcnt vmcnt(0)" ::: "memory"); }
    __builtin_amdgcn_sched_barrier(0);
  }
  __syncthreads();                                   // safe to reuse LDS

  // ---------------- epilogue: gates, h_new, s ----------------
  float (*stg)[516] = (float(*)[516])smem;   // [32 ch][512 pix + pad4]
  float ps[4][4] = {};
  #pragma unroll
  for (int ct = 0; ct < 2; ++ct){
    const int c = c0 + ct*16 + li;
    const float cbr = cb[c], cbz = cb[512 + c], xbn = cb[1024 + c], hbn = cb[1536 + c];
    #pragma unroll
    for (int mf = 0; mf < 4; ++mf){
      const int f = f0 + w*64 + mf*16 + lg*4;
      const size_t gidx = ((size_t)(b*512 + c))*1024 + f;
      f32x4 hp = *(const f32x4*)(h + gidx);
      f32x4 xt = *(const f32x4*)(x + gidx);
      f32x4 sv;
      #pragma unroll
      for (int j = 0; j < 4; ++j){
        float rr = sigm(accr[ct][mf][j] + cbr);
        float zz = sigm(accz[ct][mf][j] + cbz);
        float g  = accg1[ct][mf][j] + xbn + rr*(accg2[ct][mf][j] + hbn);
        float th = tanh_fast(g);
        float s  = (1.f - zz)*th + zz*hp[j] + xt[j];
        sv[j] = s;
        ps[mf][j] += s*s;
      }
      *(f32x4*)&stg[ct*16 + li][w*64 + mf*16 + lg*4] = sv;
    }
  }
  #pragma unroll
  for (int off = 1; off < 16; off <<= 1)
    #pragma unroll
    for (int mf = 0; mf < 4; ++mf)
      #pragma unroll
      for (int j = 0; j < 4; ++j)
        ps[mf][j] += __shfl_xor(ps[mf][j], off);
  if (li == 0){
    #pragma unroll
    for (int mf = 0; mf < 4; ++mf){
      f32x4 v; v[0]=ps[mf][0]; v[1]=ps[mf][1]; v[2]=ps[mf][2]; v[3]=ps[mf][3];
      *(f32x4*)(ssqp + (size_t)ch*65536 + pixbase + w*64 + mf*16 + lg*4) = v;
    }
  }
  __syncthreads();
  {
    const int cl = t >> 4, seg = t & 15;   // 32 rows x 16 segs of 32 cols
    u16* dst = sbf + ((size_t)(b*512 + c0 + cl))*1024 + f0 + seg*32;
    #pragma unroll
    for (int qq = 0; qq < 2; ++qq){
      f32x4 a0 = *(const f32x4*)&stg[cl][seg*32 + qq*16 + 0];
      f32x4 a1 = *(const f32x4*)&stg[cl][seg*32 + qq*16 + 4];
      f32x4 a2 = *(const f32x4*)&stg[cl][seg*32 + qq*16 + 8];
      f32x4 a3 = *(const f32x4*)&stg[cl][seg*32 + qq*16 + 12];
      short8 p0, p1;
      #pragma unroll
      for (int j = 0; j < 4; ++j){
        p0[j]   = (short)f2bf(a0[j]); p0[j+4] = (short)f2bf(a1[j]);
        p1[j]   = (short)f2bf(a2[j]); p1[j+4] = (short)f2bf(a3[j]);
      }
      *(short8*)(dst + qq*16)     = p0;
      *(short8*)(dst + qq*16 + 8) = p1;
    }
  }
}

// =====================================================================
// outnorm (validated)
// =====================================================================
extern "C" __global__ void __launch_bounds__(256)
outnorm(const float* __restrict__ ssqp, const u16* __restrict__ sbf,
        const float* __restrict__ outw, float* __restrict__ out)
{
  __shared__ float invf[1024];
  const int b = blockIdx.y, cch = blockIdx.x;
  const int t = threadIdx.x;
  f32x4 acc = {};
  #pragma unroll
  for (int p = 0; p < 16; ++p){
    f32x4 v = *(const f32x4*)(ssqp + (size_t)p*65536 + b*1024 + t*4);
    acc[0]+=v[0]; acc[1]+=v[1]; acc[2]+=v[2]; acc[3]+=v[3];
  }
  f32x4 iv;
  #pragma unroll
  for (int j = 0; j < 4; ++j) iv[j] = rsqrtf(acc[j]*(1.f/512.f) + EPSV);
  *(f32x4*)&invf[t*4] = iv;
  __syncthreads();
  for (int cl = 0; cl < 32; ++cl){
    const int c = cch*32 + cl;
    const float ow = outw[c];
    const u16* row = sbf + ((size_t)(b*512 + c))*1024;
    u16x4 sv = *(const u16x4*)(row + t*4);
    f32x4 o;
    #pragma unroll
    for (int j = 0; j < 4; ++j) o[j] = bf2f(sv[j]) * invf[t*4 + j] * ow;
    *(f32x4*)(out + ((size_t)(b*512 + c))*1024 + t*4) = o;
  }
}

// =====================================================================
// ================ FALLBACK (round-1, validated) ======================
// =====================================================================
#define FB_AXN_OFF 0
#define FB_AHM_OFF 32768
#define FB_RAW_OFF 65536
#define FB_PART_OFF 102400
#define FB_INVX_OFF 104512
#define FB_INVH_OFF 104640
#define FB_SSQ2_OFF 104784
#define FB_INVO_OFF 105936
#define FB_SMEM_BYTES 106112

extern "C" __global__ void fb_wconv(const float* __restrict__ xW, const float* __restrict__ hW,
                                    u16* __restrict__ xWb, u16* __restrict__ hWb){
  int i = blockIdx.x*256 + threadIdx.x;
  xWb[i] = f2bf(xW[i]);
  hWb[i] = f2bf(hW[i]);
}

extern "C" __global__ void __launch_bounds__(512, 2)
fb_gru(const float* __restrict__ x, const float* __restrict__ h,
       const float* __restrict__ inw, const float* __restrict__ hidw,
       const float* __restrict__ outw,
       const float* __restrict__ xb, const float* __restrict__ hmixWc,
       const float* __restrict__ hmixb, const float* __restrict__ hb,
       const u16* __restrict__ xWb, const u16* __restrict__ hWb,
       float* __restrict__ out)
{
  extern __shared__ __align__(16) char smem[];
  const int b  = blockIdx.y;
  const int f0 = blockIdx.x * 32;
  const int t  = threadIdx.x;
  u16* raw = (u16*)(smem + FB_RAW_OFF);
  float* part = (float*)(smem + FB_PART_OFF);
  {
    const int fq = t & 7, cb2 = t >> 3;
    #pragma unroll
    for (int pass = 0; pass < 8; ++pass){
      int c = pass*64 + cb2;
      f32x4 v = *(const f32x4*)(x + ((size_t)(b*512 + c))*1024 + f0 + fq*4);
      u16* d = raw + c*36 + fq*4;
      d[0] = f2bf(v[0]); d[1] = f2bf(v[1]); d[2] = f2bf(v[2]); d[3] = f2bf(v[3]);
    }
  }
  __syncthreads();
  {
    const int f = t & 31, cs = t >> 5;
    float p = 0.f;
    for (int i = 0; i < 32; ++i){ float v = bf2f(raw[(cs*32 + i)*36 + f]); p += v*v; }
    part[cs*33 + f] = p;
  }
  __syncthreads();
  if (t < 32){
    float s = 0.f;
    for (int i = 0; i < 16; ++i) s += part[i*33 + t];
    ((float*)(smem + FB_INVX_OFF))[t] = rsqrtf(s*(1.f/512.f) + EPSV);
  }
  __syncthreads();
  {
    const int f = t >> 4, cc = t & 15;
    const float iv = ((float*)(smem + FB_INVX_OFF))[f];
    #pragma unroll
    for (int it = 0; it < 4; ++it){
      int cbase = (cc + it*16)*8;
      short8 pk;
      #pragma unroll
      for (int j = 0; j < 8; ++j){
        float v = bf2f(raw[(cbase+j)*36 + f]) * iv * inw[cbase+j];
        pk[j] = (short)f2bf(v);
      }
      *(short8*)(smem + FB_AXN_OFF + f*1024 + ((cbase*2) ^ ((f&7)<<4))) = pk;
    }
  }
  __syncthreads();
  {
    const int fq = t & 7, cb2 = t >> 3;
    #pragma unroll
    for (int pass = 0; pass < 8; ++pass){
      int c = pass*64 + cb2;
      f32x4 v = *(const f32x4*)(h + ((size_t)(b*512 + c))*1024 + f0 + fq*4);
      u16* d = raw + c*36 + 1 + fq*4;
      d[0] = f2bf(v[0]); d[1] = f2bf(v[1]); d[2] = f2bf(v[2]); d[3] = f2bf(v[3]);
    }
    {
      int c = t;
      size_t base = ((size_t)(b*512 + c))*1024;
      float lv = (f0 > 0)          ? h[base + f0 - 1]  : 0.f;
      float rv = (f0 + 32 < 1024)  ? h[base + f0 + 32] : 0.f;
      raw[c*36 + 0]  = f2bf(lv);
      raw[c*36 + 33] = f2bf(rv);
    }
  }
  __syncthreads();
  {
    const int fw = t & 63, cs = t >> 6;
    if (fw < 34){
      float p = 0.f;
      for (int i = 0; i < 64; ++i){ float v = bf2f(raw[(cs*64 + i)*36 + fw]); p += v*v; }
      part[cs*35 + fw] = p;
    }
  }
  __syncthreads();
  if (t < 34){
    float s = 0.f;
    for (int i = 0; i < 8; ++i) s += part[i*35 + t];
    ((float*)(smem + FB_INVH_OFF))[t] = rsqrtf(s*(1.f/512.f) + EPSV);
  }
  __syncthreads();
  {
    const int fr = t >> 5, cc = t & 31;
    const float* invh = (const float*)(smem + FB_INVH_OFF);
    const float iL = invh[fr], iC = invh[fr + 1], iR = invh[fr + 2];
    #pragma unroll
    for (int it = 0; it < 2; ++it){
      const int cbase = (cc + it*32)*8;
      short8 o;
      #pragma unroll
      for (int j = 0; j < 8; ++j){
        int c = cbase + j;
        float hL = bf2f(raw[c*36 + fr])     * iL;
        float hC = bf2f(raw[c*36 + fr + 1]) * iC;
        float hR = bf2f(raw[c*36 + fr + 2]) * iR;
        float v = (hmixWc[c*3]*hL + hmixWc[c*3+1]*hC + hmixWc[c*3+2]*hR) * hidw[c] + hmixb[c];
        o[j] = (short)f2bf(v);
      }
      *(short8*)(smem + FB_AHM_OFF + fr*1024 + ((cbase*2) ^ ((fr&7)<<4))) = o;
    }
  }
  __syncthreads();
  const int wv = t >> 6, lane = t & 63, li = lane & 15, lg = lane >> 4;
  const int n0 = wv*64;
  f32x4 ar[2][4] = {}, az[2][4] = {}, axg[2][4] = {}, ahg[2][4] = {};
  #pragma unroll
  for (int src = 0; src < 2; ++src){
    const char* A = smem + (src ? FB_AHM_OFF : FB_AXN_OFF);
    const u16* W = src ? hWb : xWb;
    for (int k0 = 0; k0 < 512; k0 += 32){
      const int kb = (k0*2 + lg*16) ^ ((li & 7) << 4);
      short8 a0 = *(const short8*)(A + li*1024 + kb);
      short8 a1 = *(const short8*)(A + (li+16)*1024 + kb);
      #pragma unroll
      for (int nt = 0; nt < 4; ++nt){
        const u16* bp = W + (size_t)(n0 + nt*16 + li)*512 + k0 + lg*8;
        short8 br = *(const short8*)(bp);
        short8 bz = *(const short8*)(bp + 512*512);
        short8 bg = *(const short8*)(bp + 1024*512);
        ar[0][nt] = __builtin_amdgcn_mfma_f32_16x16x32_bf16(a0, br, ar[0][nt], 0,0,0);
        ar[1][nt] = __builtin_amdgcn_mfma_f32_16x16x32_bf16(a1, br, ar[1][nt], 0,0,0);
        az[0][nt] = __builtin_amdgcn_mfma_f32_16x16x32_bf16(a0, bz, az[0][nt], 0,0,0);
        az[1][nt] = __builtin_amdgcn_mfma_f32_16x16x32_bf16(a1, bz, az[1][nt], 0,0,0);
        if (src == 0){
          axg[0][nt] = __builtin_amdgcn_mfma_f32_16x16x32_bf16(a0, bg, axg[0][nt], 0,0,0);
          axg[1][nt] = __builtin_amdgcn_mfma_f32_16x16x32_bf16(a1, bg, axg[1][nt], 0,0,0);
        } else {
          ahg[0][nt] = __builtin_amdgcn_mfma_f32_16x16x32_bf16(a0, bg, ahg[0][nt], 0,0,0);
          ahg[1][nt] = __builtin_amdgcn_mfma_f32_16x16x32_bf16(a1, bg, ahg[1][nt], 0,0,0);
        }
      }
    }
  }
  float ps[8] = {0,0,0,0,0,0,0,0};
  #pragma unroll
  for (int nt = 0; nt < 4; ++nt){
    const int c = n0 + nt*16 + li;
    const float xbr = xb[c], xbz = xb[512+c], xbg = xb[1024+c];
    const float hbr = hb[c], hbz = hb[512+c], hbg = hb[1024+c];
    #pragma unroll
    for (int mt = 0; mt < 2; ++mt){
      const size_t idx = ((size_t)(b*512 + c))*1024 + f0 + mt*16 + lg*4;
      const f32x4 hp = *(const f32x4*)(h + idx);
      const f32x4 xt = *(const f32x4*)(x + idx);
      f32x4 sv;
      #pragma unroll
      for (int j = 0; j < 4; ++j){
        float rr = sigm(ar[mt][nt][j] + xbr + hbr);
        float zz = sigm(az[mt][nt][j] + xbz + hbz);
        float g  = axg[mt][nt][j] + xbg + rr*(ahg[mt][nt][j] + hbg);
        float th = tanh_fast(g);
        float hv = (1.f - zz)*th + zz*hp[j];
        float s  = hv + xt[j];
        sv[j] = s;
        ps[mt*4 + j] += s*s;
      }
      ar[mt][nt] = sv;
    }
  }
  #pragma unroll
  for (int off = 1; off < 16; off <<= 1){
    #pragma unroll
    for (int p = 0; p < 8; ++p) ps[p] += __shfl_xor(ps[p], off);
  }
  __syncthreads();
  float* stg = (float*)(smem + FB_AXN_OFF);
  #pragma unroll
  for (int nt = 0; nt < 4; ++nt){
    const int n = n0 + nt*16 + li;
    #pragma unroll
    for (int mt = 0; mt < 2; ++mt){
      const int m0 = mt*16 + lg*4;
      *(f32x4*)(stg + n*32 + (m0 ^ ((n & 7) << 2))) = ar[mt][nt];
    }
  }
  float* sq2 = (float*)(smem + FB_SSQ2_OFF);
  if (li == 0){
    #pragma unroll
    for (int p = 0; p < 8; ++p){
      int m = (p >> 2)*16 + lg*4 + (p & 3);
      sq2[m*9 + wv] = ps[p];
    }
  }
  __syncthreads();
  if (t < 32){
    float s = 0.f;
    for (int i = 0; i < 8; ++i) s += sq2[t*9 + i];
    ((float*)(smem + FB_INVO_OFF))[t] = rsqrtf(s*(1.f/512.f) + EPSV);
  }
  __syncthreads();
  {
    const float* invO = (const float*)(smem + FB_INVO_OFF);
    const int cb2 = t >> 3, chh = t & 7;
    #pragma unroll
    for (int pass = 0; pass < 8; ++pass){
      int c = pass*64 + cb2;
      int base = (chh*4) ^ ((c & 7) << 2);
      f32x4 v = *(const f32x4*)(stg + c*32 + base);
      float ow = outw[c];
      f32x4 o;
      #pragma unroll
      for (int j = 0; j < 4; ++j) o[j] = v[j] * invO[chh*4 + j] * ow;
      *(f32x4*)(out + ((size_t)(b*512 + c))*1024 + f0 + chh*4) = o;
    }
  }
}

// =====================================================================
extern "C" void kernel_launch(void* const* d_in, const int* in_sizes, int n_in,
                              void* d_out, int out_size, void* d_ws, size_t ws_size,
                              hipStream_t stream){
  (void)in_sizes; (void)n_in; (void)out_size;
  const float* x      = (const float*)d_in[0];
  const float* h      = (const float*)d_in[1];
  const float* inw    = (const float*)d_in[2];
  const float* hidw   = (const float*)d_in[3];
  const float* outw   = (const float*)d_in[4];
  const float* xW     = (const float*)d_in[5];
  const float* xb     = (const float*)d_in[6];
  const float* hmixW  = (const float*)d_in[7];
  const float* hmixb  = (const float*)d_in[8];
  const float* hW     = (const float*)d_in[9];
  const float* hb     = (const float*)d_in[10];

  if (ws_size >= (size_t)WS_NEED){
    u16*   xWb  = (u16*)((char*)d_ws + WS_WXB);
    u16*   hWb  = (u16*)((char*)d_ws + WS_WHB);
    float* cbw  = (float*)((char*)d_ws + WS_CB);
    float* ssqp = (float*)((char*)d_ws + WS_SSQP);
    u16*   sbf  = (u16*)((char*)d_ws + WS_SBF);
    u16*   Ax   = (u16*)d_out;                    // A_x [65536][512]

    hipFuncSetAttribute(reinterpret_cast<const void*>(gemm_gates),
                        hipFuncAttributeMaxDynamicSharedMemorySize, GG_SMEM);

    wprep<<<1536, 256, 0, stream>>>(xW, hW, inw, hidw, xb, hmixb, hb, xWb, hWb, cbw);
    wbuild<<<dim3(4, 64), 256, 0, stream>>>(x, h, hmixW, Ax, Ax + 33554432);
    gemm_gates<<<2048, 512, GG_SMEM, stream>>>(x, h, Ax, xWb, hWb, cbw, ssqp, sbf);
    outnorm<<<dim3(16, 64), 256, 0, stream>>>(ssqp, sbf, outw, (float*)d_out);
  } else {
    u16* xWb = (u16*)d_ws;
    u16* hWb = xWb + 786432;
    hipFuncSetAttribute(reinterpret_cast<const void*>(fb_gru),
                        hipFuncAttributeMaxDynamicSharedMemorySize, FB_SMEM_BYTES);
    fb_wconv<<<3072, 256, 0, stream>>>(xW, hW, xWb, hWb);
    dim3 grid(32, 64);
    fb_gru<<<grid, 512, FB_SMEM_BYTES, stream>>>(x, h, inw, hidw, outw,
                                                 xb, hmixW, hmixb, hb,
                                                 xWb, hWb, (float*)d_out);
  }
}